// Round 10
// baseline (19.982 us; speedup 1.0000x reference)
//
#include <hip/hip_runtime.h>
#include <hip/hip_bf16.h>
#include <float.h>

// MeshLoss: out = mean_b,m( min_n |pc[b,m]-top[b,n]|^2 ) + mean((bottom-fem_bottom)^2)
// network_mesh (4,3,32,16,32) f32, pc (4,3,16384) f32, fem_mesh (4,3,32,16,32) f32.
// top[b,n] = network_mesh[b,:, n>>5, 15, n&31], n in [0,1024)
//
// |p-t|^2 = |p|^2 + (|t|^2 - 2 p.t): d' = fma(-2px,tx, fma(-2py,ty,
// fma(-2pz,tz, t2))) = 3 FMA/pair, folded pairwise into v_min3_f32.
//
// R9 post-mortem: R7->R9 K1 LDS diet gave ZERO gain -> total no longer tracks
// K1's pipes; the second dispatch (~4-5us of gap+launch+tiny-kernel) is the
// biggest remaining line item. R4 calibration: memset + single kernel carried
// only ~2.7us of fixed overhead. R10: SINGLE dispatch — R9's lean K1 ends with
// one atomicAdd per block into out[0] (zeroed by a 4-byte memset node).
// No ws, no K2. Atomic ordering noise ~1e-6 << 4.2e-2 threshold (R3/R5/R6
// all passed with same-address block atomics).
//
// K1: 256 blocks x 512 thr (1 block/CU). Block = (batch, 256-pt chunk).
//     Tops staged SoA (xs/ys/zs, no t2; float4 reads = 6 ds_read_b128 per
//     8 tops); 8 waves PARTITION the 1024 tops (128 each); every wave covers
//     all 256 block points (4/lane). Per-wave mins (+|p|^2) -> pm[8][256] ->
//     8-way min by t<256; fem slice (180 float4 pairs) folded in; block
//     partial -> atomicAdd(out).

#define NM_BATCH_STRIDE 49152     // 3*32*16*32 (== pc batch stride)
#define CH_STRIDE       16384
#define NTOP            1024
#define TOPS_PER_WAVE   128       // 1024 / 8 waves
#define NBLK            256
#define NTHR            512
#define FEM_PER_BLK     180       // 46080 float4 pairs / 256 blocks

__global__ __launch_bounds__(NTHR) void meshloss_fused(
    const float* __restrict__ nm,
    const float* __restrict__ pc,
    const float* __restrict__ fem,
    float* __restrict__ out)
{
    __shared__ __align__(16) float xs[NTOP];   // 4 KB each
    __shared__ __align__(16) float ys[NTOP];
    __shared__ __align__(16) float zs[NTOP];
    __shared__ float pm[8 * 256];              // 8 KB per-wave partial mins
    __shared__ float wsum[8];

    const int t     = threadIdx.x;
    const int b     = blockIdx.x >> 6;      // batch
    const int chunk = blockIdx.x & 63;      // 256-point chunk
    const int w     = t >> 6;               // wave 0..7
    const int l     = t & 63;               // lane

    // ---- stage tops (j==15 slice) as SoA, no t2 ----
    const float* nmb = nm + b * NM_BATCH_STRIDE;
    #pragma unroll
    for (int p0 = 0; p0 < NTOP; p0 += NTHR) {
        const int p = p0 + t;
        const int i = p >> 5, k = p & 31;
        const int base = i * 512 + 480 + k;          // (i*16+15)*32 + k
        xs[p] = nmb[0 * CH_STRIDE + base];
        ys[p] = nmb[1 * CH_STRIDE + base];
        zs[p] = nmb[2 * CH_STRIDE + base];
    }

    // ---- this lane's 4 points (same 4 points in every wave) ----
    const float* pcb = pc + b * NM_BATCH_STRIDE;
    const int m0 = chunk * 256 + l;                  // point p_j = l + j*64
    float px2[4], py2[4], pz2[4], pp[4], mn[4];
    #pragma unroll
    for (int j = 0; j < 4; ++j) {
        const int m = m0 + j * 64;
        float x = pcb[m];
        float y = pcb[CH_STRIDE + m];
        float z = pcb[2 * CH_STRIDE + m];
        pp[j]  = x * x + y * y + z * z;
        px2[j] = -2.0f * x;
        py2[j] = -2.0f * y;
        pz2[j] = -2.0f * z;
        mn[j]  = FLT_MAX;
    }
    __syncthreads();

    // ---- wave w scans its 128-top share for all 4 points/lane ----
    const float4* xs4 = reinterpret_cast<const float4*>(xs);
    const float4* ys4 = reinterpret_cast<const float4*>(ys);
    const float4* zs4 = reinterpret_cast<const float4*>(zs);
    const int base4 = w * (TOPS_PER_WAVE / 4);       // float4 index of share

    #pragma unroll 2
    for (int g = 0; g < TOPS_PER_WAVE / 8; ++g) {
        float4 X0 = xs4[base4 + 2 * g];
        float4 X1 = xs4[base4 + 2 * g + 1];
        float4 Y0 = ys4[base4 + 2 * g];
        float4 Y1 = ys4[base4 + 2 * g + 1];
        float4 Z0 = zs4[base4 + 2 * g];
        float4 Z1 = zs4[base4 + 2 * g + 1];
        float tx[8] = {X0.x, X0.y, X0.z, X0.w, X1.x, X1.y, X1.z, X1.w};
        float ty[8] = {Y0.x, Y0.y, Y0.z, Y0.w, Y1.x, Y1.y, Y1.z, Y1.w};
        float tz[8] = {Z0.x, Z0.y, Z0.z, Z0.w, Z1.x, Z1.y, Z1.z, Z1.w};
        float t2[8];
        #pragma unroll
        for (int e = 0; e < 8; ++e)
            t2[e] = __builtin_fmaf(tx[e], tx[e],
                    __builtin_fmaf(ty[e], ty[e], tz[e] * tz[e]));
        #pragma unroll
        for (int j = 0; j < 4; ++j) {
            #define DISTD(e) __builtin_fmaf(px2[j], tx[e], \
                             __builtin_fmaf(py2[j], ty[e], \
                             __builtin_fmaf(pz2[j], tz[e], t2[e])))
            float d0 = DISTD(0);
            float d1 = DISTD(1);
            float d2 = DISTD(2);
            float d3 = DISTD(3);
            float d4 = DISTD(4);
            float d5 = DISTD(5);
            float d6 = DISTD(6);
            float d7 = DISTD(7);
            #undef DISTD
            mn[j] = fminf(mn[j], fminf(d0, d1));   // v_min3_f32
            mn[j] = fminf(mn[j], fminf(d2, d3));
            mn[j] = fminf(mn[j], fminf(d4, d5));
            mn[j] = fminf(mn[j], fminf(d6, d7));
        }
    }

    // ---- per-wave partial (+|p|^2, commutes with cross-wave min) ----
    #pragma unroll
    for (int j = 0; j < 4; ++j)
        pm[w * 256 + l + j * 64] = mn[j] + pp[j];
    __syncthreads();

    // ---- 8-way min combine (threads 0..255) ----
    float v = 0.0f;
    if (t < 256) {
        float d = pm[t];
        #pragma unroll
        for (int ww = 1; ww < 8; ++ww)
            d = fminf(d, pm[ww * 256 + t]);
        v = d * (1.0f / 65536.0f);
    }

    // ---- fem MSE slice: 180 float4 pairs per block ----
    if (t < FEM_PER_BLK) {
        const int q   = blockIdx.x * FEM_PER_BLK + t;   // < 46080
        const int bci = q / 120;
        const int r   = q - bci * 120;
        const int s   = bci * 128 + r;
        float4 a = reinterpret_cast<const float4*>(nm)[s];
        float4 f = reinterpret_cast<const float4*>(fem)[s];
        float dx = a.x - f.x, dy = a.y - f.y, dz = a.z - f.z, dw = a.w - f.w;
        v += (dx * dx + dy * dy + dz * dz + dw * dw) * (1.0f / 184320.0f);
    }

    // ---- block reduce (8 waves) + ONE atomicAdd per block ----
    for (int o = 32; o > 0; o >>= 1) v += __shfl_down(v, o, 64);
    if (l == 0) wsum[w] = v;
    __syncthreads();
    if (t == 0) {
        float s = 0.0f;
        #pragma unroll
        for (int ww = 0; ww < 8; ++ww) s += wsum[ww];
        atomicAdd(out, s);
    }
}

extern "C" void kernel_launch(void* const* d_in, const int* in_sizes, int n_in,
                              void* d_out, int out_size, void* d_ws, size_t ws_size,
                              hipStream_t stream) {
    const float* nm  = (const float*)d_in[0];
    const float* pc  = (const float*)d_in[1];
    const float* fem = (const float*)d_in[2];
    float* out = (float*)d_out;

    hipMemsetAsync(out, 0, sizeof(float), stream);
    meshloss_fused<<<NBLK, NTHR, 0, stream>>>(nm, pc, fem, out);
}

// Round 11
// 14.563 us; speedup vs baseline: 1.3721x; 1.3721x over previous
//
#include <hip/hip_runtime.h>
#include <hip/hip_bf16.h>
#include <float.h>

// MeshLoss: out = mean_b,m( min_n |pc[b,m]-top[b,n]|^2 ) + mean((bottom-fem_bottom)^2)
// network_mesh (4,3,32,16,32) f32, pc (4,3,16384) f32, fem_mesh (4,3,32,16,32) f32.
// top[b,n] = network_mesh[b,:, n>>5, 15, n&31], n in [0,1024)
//
// |p-t|^2 = |p|^2 + (|t|^2 - 2 p.t): d' = fma(-2px,tx, fma(-2py,ty,
// fma(-2pz,tz, t2))) = 3 FMA/pair, folded pairwise into v_min3_f32.
//
// R10 post-mortem: 256 same-address atomicAdds ≈ +5us tail (consistent across
// R3/R5/R7/R9/R10) -> plain stores + tiny K2 stays. K1 is LATENCY-bound at
// 2 waves/SIMD (R7->R9 LDS diet changed nothing). R11: 1024-thread blocks ->
// 16 waves = 4 waves/SIMD; wave-partitioning the tops keeps LDS reads and
// VALU inst count exactly invariant, only latency hiding doubles. Tail
// parallelized: min-combine (t<256) overlaps fem slice (t in [256,436)).
//
// K1: 256 blocks x 1024 thr (1 block/CU). Block = (batch, 256-pt chunk).
//     Tops staged SoA (xs/ys/zs, 1 top/thread); 16 waves partition tops
//     (64 each); every wave covers all 256 block points (4/lane).
//     Per-wave mins (+|p|^2) -> pm[16][256] -> 16-way min; fem slice
//     (180 float4 pairs) on threads 256..435; block partial -> ws[block].
// K2: 1 wave: fixed-order sum of 256 partials -> out[0]. No atomics.

#define NM_BATCH_STRIDE 49152     // 3*32*16*32 (== pc batch stride)
#define CH_STRIDE       16384
#define NTOP            1024
#define NWAVES          16
#define TOPS_PER_WAVE   64        // 1024 / 16 waves
#define NBLK            256
#define NTHR            1024
#define FEM_PER_BLK     180       // 46080 float4 pairs / 256 blocks

__global__ __launch_bounds__(NTHR) void meshloss_fused(
    const float* __restrict__ nm,
    const float* __restrict__ pc,
    const float* __restrict__ fem,
    float* __restrict__ ws)
{
    __shared__ __align__(16) float xs[NTOP];   // 4 KB each
    __shared__ __align__(16) float ys[NTOP];
    __shared__ __align__(16) float zs[NTOP];
    __shared__ float pm[NWAVES * 256];         // 16 KB per-wave partial mins
    __shared__ float wsum[NWAVES];

    const int t     = threadIdx.x;
    const int b     = blockIdx.x >> 6;      // batch
    const int chunk = blockIdx.x & 63;      // 256-point chunk
    const int w     = t >> 6;               // wave 0..15
    const int l     = t & 63;               // lane

    // ---- stage tops (j==15 slice) as SoA: one top per thread ----
    const float* nmb = nm + b * NM_BATCH_STRIDE;
    {
        const int i = t >> 5, k = t & 31;
        const int base = i * 512 + 480 + k;          // (i*16+15)*32 + k
        xs[t] = nmb[0 * CH_STRIDE + base];
        ys[t] = nmb[1 * CH_STRIDE + base];
        zs[t] = nmb[2 * CH_STRIDE + base];
    }

    // ---- this lane's 4 points (same 4 points in every wave) ----
    const float* pcb = pc + b * NM_BATCH_STRIDE;
    const int m0 = chunk * 256 + l;                  // point p_j = l + j*64
    float px2[4], py2[4], pz2[4], pp[4], mn[4];
    #pragma unroll
    for (int j = 0; j < 4; ++j) {
        const int m = m0 + j * 64;
        float x = pcb[m];
        float y = pcb[CH_STRIDE + m];
        float z = pcb[2 * CH_STRIDE + m];
        pp[j]  = x * x + y * y + z * z;
        px2[j] = -2.0f * x;
        py2[j] = -2.0f * y;
        pz2[j] = -2.0f * z;
        mn[j]  = FLT_MAX;
    }
    __syncthreads();

    // ---- wave w scans its 64-top share for all 4 points/lane ----
    const float4* xs4 = reinterpret_cast<const float4*>(xs);
    const float4* ys4 = reinterpret_cast<const float4*>(ys);
    const float4* zs4 = reinterpret_cast<const float4*>(zs);
    const int base4 = w * (TOPS_PER_WAVE / 4);       // float4 index of share

    #pragma unroll 2
    for (int g = 0; g < TOPS_PER_WAVE / 8; ++g) {
        float4 X0 = xs4[base4 + 2 * g];
        float4 X1 = xs4[base4 + 2 * g + 1];
        float4 Y0 = ys4[base4 + 2 * g];
        float4 Y1 = ys4[base4 + 2 * g + 1];
        float4 Z0 = zs4[base4 + 2 * g];
        float4 Z1 = zs4[base4 + 2 * g + 1];
        float tx[8] = {X0.x, X0.y, X0.z, X0.w, X1.x, X1.y, X1.z, X1.w};
        float ty[8] = {Y0.x, Y0.y, Y0.z, Y0.w, Y1.x, Y1.y, Y1.z, Y1.w};
        float tz[8] = {Z0.x, Z0.y, Z0.z, Z0.w, Z1.x, Z1.y, Z1.z, Z1.w};
        float t2[8];
        #pragma unroll
        for (int e = 0; e < 8; ++e)
            t2[e] = __builtin_fmaf(tx[e], tx[e],
                    __builtin_fmaf(ty[e], ty[e], tz[e] * tz[e]));
        #pragma unroll
        for (int j = 0; j < 4; ++j) {
            #define DISTD(e) __builtin_fmaf(px2[j], tx[e], \
                             __builtin_fmaf(py2[j], ty[e], \
                             __builtin_fmaf(pz2[j], tz[e], t2[e])))
            float d0 = DISTD(0);
            float d1 = DISTD(1);
            float d2 = DISTD(2);
            float d3 = DISTD(3);
            float d4 = DISTD(4);
            float d5 = DISTD(5);
            float d6 = DISTD(6);
            float d7 = DISTD(7);
            #undef DISTD
            mn[j] = fminf(mn[j], fminf(d0, d1));   // v_min3_f32
            mn[j] = fminf(mn[j], fminf(d2, d3));
            mn[j] = fminf(mn[j], fminf(d4, d5));
            mn[j] = fminf(mn[j], fminf(d6, d7));
        }
    }

    // ---- per-wave partial (+|p|^2, commutes with cross-wave min) ----
    #pragma unroll
    for (int j = 0; j < 4; ++j)
        pm[w * 256 + l + j * 64] = mn[j] + pp[j];
    __syncthreads();

    // ---- tail, parallel across waves: min combine (t<256) | fem (256..435) ----
    float v = 0.0f;
    if (t < 256) {
        float d = pm[t];
        #pragma unroll
        for (int ww = 1; ww < NWAVES; ++ww)
            d = fminf(d, pm[ww * 256 + t]);
        v = d * (1.0f / 65536.0f);
    } else if (t < 256 + FEM_PER_BLK) {
        const int q   = blockIdx.x * FEM_PER_BLK + (t - 256);   // < 46080
        const int bci = q / 120;
        const int r   = q - bci * 120;
        const int s   = bci * 128 + r;
        float4 a = reinterpret_cast<const float4*>(nm)[s];
        float4 f = reinterpret_cast<const float4*>(fem)[s];
        float dx = a.x - f.x, dy = a.y - f.y, dz = a.z - f.z, dw = a.w - f.w;
        v = (dx * dx + dy * dy + dz * dz + dw * dw) * (1.0f / 184320.0f);
    }

    // ---- block reduce (16 waves) + plain store of block partial ----
    for (int o = 32; o > 0; o >>= 1) v += __shfl_down(v, o, 64);
    if (l == 0) wsum[w] = v;
    __syncthreads();
    if (t == 0) {
        float s = 0.0f;
        #pragma unroll
        for (int ww = 0; ww < NWAVES; ++ww) s += wsum[ww];
        ws[blockIdx.x] = s;
    }
}

__global__ __launch_bounds__(64) void meshloss_final(
    const float* __restrict__ ws, float* __restrict__ out)
{
    const float4 a = reinterpret_cast<const float4*>(ws)[threadIdx.x];
    float v = (a.x + a.y) + (a.z + a.w);
    for (int o = 32; o > 0; o >>= 1) v += __shfl_down(v, o, 64);
    if (threadIdx.x == 0) out[0] = v;
}

extern "C" void kernel_launch(void* const* d_in, const int* in_sizes, int n_in,
                              void* d_out, int out_size, void* d_ws, size_t ws_size,
                              hipStream_t stream) {
    const float* nm  = (const float*)d_in[0];
    const float* pc  = (const float*)d_in[1];
    const float* fem = (const float*)d_in[2];
    float* out = (float*)d_out;
    float* ws  = (float*)d_ws;

    meshloss_fused<<<NBLK, NTHR, 0, stream>>>(nm, pc, fem, ws);
    meshloss_final<<<1, 64, 0, stream>>>(ws, out);
}